// Round 1
// baseline (224.132 us; speedup 1.0000x reference)
//
#include <hip/hip_runtime.h>
#include <hip/hip_bf16.h>
#include <stdint.h>

typedef unsigned short u16;
typedef unsigned int   u32;
typedef __bf16 bf16x8 __attribute__((ext_vector_type(8)));
typedef float  f32x4  __attribute__((ext_vector_type(4)));

#define BATCH 32
#define CIN   128
#define HH    56
#define WW    56
#define OC    256
#define HP    58
#define WP    58
#define PLANE  (HH*WW)    // 3136
#define KDIM   1152       // CIN*9
#define NT     18         // K tiles of 64 (KDIM/64)

#define XPAD_ELEMS (BATCH*HP*WP*CIN)   // NHWC padded bf16: 13,778,944
#define W3_ELEMS   (OC*KDIM)           // 294,912 bf16

#define GLDS16(g, l) __builtin_amdgcn_global_load_lds( \
    (const __attribute__((address_space(1))) void*)(g), \
    (__attribute__((address_space(3))) void*)(l), 16, 0, 0)

// ---- prep 0: zero top/bottom padded rows (h=0 and h=57 per image) ----
__global__ void zero_border(uint4* __restrict__ xp4) {
    int i = blockIdx.x * 256 + threadIdx.x;       // uint4 index
    if (i >= 64 * 928) return;                    // 64 rows x 928 uint4/row
    int row = i / 928;
    int off = i - row * 928;
    int b = row >> 1;
    int h = (row & 1) ? (HP - 1) : 0;
    xp4[((size_t)(b * HP + h) * WP * CIN) / 8 + off] = (uint4){0, 0, 0, 0};
}

// ---- prep 1: NCHW fp32 -> NHWC bf16, interior + left/right borders ----
__global__ __launch_bounds__(256) void pad_tr(const float* __restrict__ x,
                                              u16* __restrict__ xpad) {
    __shared__ u16 T16[56 * 130];   // [w][c], +2 pad -> bank stride 65 dwords
    const int h = blockIdx.x;
    const int b = blockIdx.y;
    const int tid = threadIdx.x;

    const float* src = x + (size_t)b * CIN * PLANE + h * WW;
#pragma unroll
    for (int j = 0; j < 28; ++j) {              // 28*256 = 7168 = 128*56
        int flat = j * 256 + tid;
        int c = flat / 56;
        int w = flat - c * 56;
        float v = src[(size_t)c * PLANE + w];
        __hip_bfloat16 bv = __float2bfloat16(v);
        T16[w * 130 + c] = *(u16*)&bv;
    }
    __syncthreads();

    const u32* T32 = (const u32*)T16;
    uint4* dst = (uint4*)(xpad + (size_t)(b * HP + h + 1) * WP * CIN);
#pragma unroll
    for (int j = 0; j < 4; ++j) {
        int g = j * 256 + tid;
        if (g < 928) {
            int wp = g >> 4, cq = g & 15;       // 16 uint4 = 128 ch per wp
            uint4 v = (uint4){0, 0, 0, 0};
            if (wp >= 1 && wp <= 56) {
                int w = wp - 1;
                v.x = T32[w * 65 + cq * 4 + 0];
                v.y = T32[w * 65 + cq * 4 + 1];
                v.z = T32[w * 65 + cq * 4 + 2];
                v.w = T32[w * 65 + cq * 4 + 3];
            }
            dst[g] = v;
        }
    }
}

// ---- prep 2: W[OC][C*9] fp32 -> bf16, layout [T=18][oc 256][64k], with the
// 8-chunk rotation PRE-APPLIED so conv_main's W staging is a linear copy.
// K-tile T covers r = T>>1 (kh*3+kw), channels (T&1)*64 .. +63.
// LDS row within half rl = oc&127; rot = (rl>>1)&7; position p stores true
// chunk ((p - rot)&7).
__global__ void pack_w(const float* __restrict__ W, u16* __restrict__ w3) {
    int o = blockIdx.x * blockDim.x + threadIdx.x;
    if (o >= W3_ELEMS) return;
    int T   = o >> 14;            // /16384
    int rem = o & 16383;
    int oc  = rem >> 6;
    int kk  = rem & 63;
    int p   = kk >> 3;
    int e   = kk & 7;
    int rot = ((oc & 127) >> 1) & 7;
    int c64 = ((p - rot) & 7) * 8 + e;
    int r   = T >> 1;
    int c128 = (T & 1) * 64 + c64;
    float val = W[oc * KDIM + c128 * 9 + r];
    __hip_bfloat16 bv = __float2bfloat16(val);
    w3[o] = *(u16*)&bv;
}

// ---------------- main: implicit GEMM, 256x256 tile, BK=64, 8-phase ----------
// 512 threads = 8 waves (2 spatial-half x 4 oc-quarter). Per-wave output is
// half-interleaved: oc cols {wn*32..+31} in BOTH oc-halves, spatial rows
// {wm*64..+63} in BOTH spatial-halves -> half-slot last-reads stagger:
//   Wh0: P1, Xh0: P1, Wh1: P2, Xh1: P3.
// Stage cadence (one half-tile = 2 GLDS16/thread per phase), WAR-safe since
// each stage targets a slot whose last ds_read was >=1 phase earlier:
//   P1: (t+1).Xh1   P2: (t+2).Wh0   P3: (t+2).Xh0   P4: (t+2).Wh1
// vmcnt(6) ONLY at P4 (3 half-tiles in flight) guarantees tile t+1 landed.
// Raw s_barrier (never __syncthreads) so the DMA queue is never drained to 0
// in steady state. setprio(1) around each 16-MFMA cluster.
// LDS rows are 128 B (64 bf16); chunk-rotation swizzle rot=(row>>1)&7 keeps
// ds_read_b128 conflict-free (verified 0 conflicts at BK=32; same property).
__global__ __launch_bounds__(512, 2) void conv_main(
    const u16* __restrict__ xpad,
    const u16* __restrict__ w3,
    const float* __restrict__ bias,
    float* __restrict__ out)
{
    __shared__ __align__(16) u16 WL[2 * 2 * 128 * 64];  // [buf][half][128][64] 64KB
    __shared__ __align__(16) u16 XL[2 * 2 * 128 * 64];  // 64KB

    const int tid  = threadIdx.x;
    const int lane = tid & 63;
    const int wv   = tid >> 6;
    const int wm   = wv >> 2;       // spatial 64-row slice within each half
    const int wn   = wv & 3;        // oc 32-col slice within each half
    const int l16  = lane & 15;
    const int quad = lane >> 4;

    // XCD-aware swizzle: 392 = 8 * 49 (divisible -> simple form is bijective)
    const int bid  = blockIdx.x;
    const int tile = (bid & 7) * 49 + (bid >> 3);
    const int m0   = tile * 256;

    // ---- staging geometry: instr i covers rows (wv*2+i)*8..+7, pos lane&7 ----
    const int srow8 = lane >> 3;
    const int spos  = lane & 7;
    size_t xsrc[2][2];
#pragma unroll
    for (int h = 0; h < 2; ++h)
#pragma unroll
        for (int i = 0; i < 2; ++i) {
            int r  = (wv * 2 + i) * 8 + srow8;          // row within half
            int q  = (spos - ((r >> 1) & 7)) & 7;       // source chunk
            int m  = m0 + h * 128 + r;
            int b  = m / PLANE;
            int s  = m - b * PLANE;
            int hh = s / WW;
            int ww = s - hh * WW;
            xsrc[h][i] = ((size_t)((b * HP + hh) * WP + ww) * CIN) * 2 + (size_t)q * 16;
        }
    const char* xb  = (const char*)xpad;
    const char* w3b = (const char*)w3;
    const int dstat     = wv * 2048;            // LDS dst (wave-uniform) base
    const int wsrc_lane = wv * 2048 + lane * 16;

    auto xkoff = [&](int kt) -> int {
        int r9 = kt >> 1;
        int kh = (r9 * 11) >> 5;                // r9/3 for r9 in 0..8
        int kw = r9 - kh * 3;
        return ((kh * WP + kw) * CIN + (kt & 1) * 64) * 2;
    };
    auto stageW = [&](int kt, int h) {
        const char* src = w3b + (size_t)kt * 32768 + h * 16384 + wsrc_lane;
        char* dst = (char*)WL + (kt & 1) * 32768 + h * 16384 + dstat;
        GLDS16(src,        dst);
        GLDS16(src + 1024, dst + 1024);
    };
    auto stageX = [&](int kt, int h, int xko) {
        char* dst = (char*)XL + (kt & 1) * 32768 + h * 16384 + dstat;
        GLDS16(xb + xsrc[h][0] + xko, dst);
        GLDS16(xb + xsrc[h][1] + xko, dst + 1024);
    };

    // frag ds_read byte offsets within a half-slot (s=0; s=1 is ^64)
    int woff[2], xoff[4];
#pragma unroll
    for (int j = 0; j < 2; ++j) {
        int r = wn * 32 + j * 16 + l16;
        woff[j] = r * 128 + (((quad + (r >> 1)) & 7) << 4);
    }
#pragma unroll
    for (int j = 0; j < 4; ++j) {
        int r = wm * 64 + j * 16 + l16;
        xoff[j] = r * 128 + (((quad + (r >> 1)) & 7) << 4);
    }

    f32x4 acc[4][8];
#pragma unroll
    for (int f = 0; f < 4; ++f) {
        const int ob = (f >> 1) * 128 + wn * 32 + (f & 1) * 16 + quad * 4;
        f32x4 bv = *(const f32x4*)&bias[ob];
#pragma unroll
        for (int g = 0; g < 8; ++g) acc[f][g] = bv;
    }

    // ---- prologue: tile0 full + tile1 {Wh0,Xh0,Wh1} (14 loads in flight) ----
    stageW(0, 0); stageW(0, 1);
    stageX(0, 0, xkoff(0)); stageX(0, 1, xkoff(0));
    stageW(1, 0); stageX(1, 0, xkoff(1)); stageW(1, 1);
    asm volatile("s_waitcnt vmcnt(6)" ::: "memory");   // tile0's 8 loads landed
    __builtin_amdgcn_sched_barrier(0);
    __builtin_amdgcn_s_barrier();

#pragma unroll 1
    for (int kt = 0; kt < NT; ++kt) {
        const char* Wb = (const char*)WL + (kt & 1) * 32768;
        const char* Xb = (const char*)XL + (kt & 1) * 32768;
        const bool st2 = (kt + 2 < NT);

        // ================= P1: Wh0 x Xh0 =================
        bf16x8 wlo[2][2], xlo[4][2];
#pragma unroll
        for (int j = 0; j < 2; ++j) {
            wlo[j][0] = *(const bf16x8*)(Wb + woff[j]);
            wlo[j][1] = *(const bf16x8*)(Wb + (woff[j] ^ 64));
        }
#pragma unroll
        for (int j = 0; j < 4; ++j) {
            xlo[j][0] = *(const bf16x8*)(Xb + xoff[j]);
            xlo[j][1] = *(const bf16x8*)(Xb + (xoff[j] ^ 64));
        }
        if (kt + 1 < NT) stageX(kt + 1, 1, xkoff(kt + 1));
        __builtin_amdgcn_s_barrier();
        asm volatile("s_waitcnt lgkmcnt(0)" ::: "memory");
        __builtin_amdgcn_sched_barrier(0);
        __builtin_amdgcn_s_setprio(1);
#pragma unroll
        for (int f = 0; f < 2; ++f)
#pragma unroll
            for (int g = 0; g < 4; ++g)
#pragma unroll
                for (int s = 0; s < 2; ++s)
                    acc[f][g] = __builtin_amdgcn_mfma_f32_16x16x32_bf16(
                        wlo[f][s], xlo[g][s], acc[f][g], 0, 0, 0);
        __builtin_amdgcn_s_setprio(0);
        __builtin_amdgcn_s_barrier();

        // ================= P2: Wh1 x Xh0 =================
        bf16x8 whi[2][2];
#pragma unroll
        for (int j = 0; j < 2; ++j) {
            whi[j][0] = *(const bf16x8*)(Wb + 16384 + woff[j]);
            whi[j][1] = *(const bf16x8*)(Wb + 16384 + (woff[j] ^ 64));
        }
        if (st2) stageW(kt + 2, 0);
        __builtin_amdgcn_s_barrier();
        asm volatile("s_waitcnt lgkmcnt(0)" ::: "memory");
        __builtin_amdgcn_sched_barrier(0);
        __builtin_amdgcn_s_setprio(1);
#pragma unroll
        for (int f = 0; f < 2; ++f)
#pragma unroll
            for (int g = 0; g < 4; ++g)
#pragma unroll
                for (int s = 0; s < 2; ++s)
                    acc[2 + f][g] = __builtin_amdgcn_mfma_f32_16x16x32_bf16(
                        whi[f][s], xlo[g][s], acc[2 + f][g], 0, 0, 0);
        __builtin_amdgcn_s_setprio(0);
        __builtin_amdgcn_s_barrier();

        // ================= P3: Wh0 x Xh1 =================
        bf16x8 xhi[4][2];
#pragma unroll
        for (int j = 0; j < 4; ++j) {
            xhi[j][0] = *(const bf16x8*)(Xb + 16384 + xoff[j]);
            xhi[j][1] = *(const bf16x8*)(Xb + 16384 + (xoff[j] ^ 64));
        }
        if (st2) stageX(kt + 2, 0, xkoff(kt + 2));
        __builtin_amdgcn_s_barrier();
        asm volatile("s_waitcnt lgkmcnt(0)" ::: "memory");
        __builtin_amdgcn_sched_barrier(0);
        __builtin_amdgcn_s_setprio(1);
#pragma unroll
        for (int f = 0; f < 2; ++f)
#pragma unroll
            for (int g = 0; g < 4; ++g)
#pragma unroll
                for (int s = 0; s < 2; ++s)
                    acc[f][4 + g] = __builtin_amdgcn_mfma_f32_16x16x32_bf16(
                        wlo[f][s], xhi[g][s], acc[f][4 + g], 0, 0, 0);
        __builtin_amdgcn_s_setprio(0);
        __builtin_amdgcn_s_barrier();

        // ================= P4: Wh1 x Xh1 (no ds_reads; all from regs) =======
        if (st2) stageW(kt + 2, 1);
        __builtin_amdgcn_s_barrier();
        __builtin_amdgcn_s_setprio(1);
#pragma unroll
        for (int f = 0; f < 2; ++f)
#pragma unroll
            for (int g = 0; g < 4; ++g)
#pragma unroll
                for (int s = 0; s < 2; ++s)
                    acc[2 + f][4 + g] = __builtin_amdgcn_mfma_f32_16x16x32_bf16(
                        whi[f][s], xhi[g][s], acc[2 + f][4 + g], 0, 0, 0);
        __builtin_amdgcn_s_setprio(0);
        // counted drain: steady state keeps 3 half-tiles (6 loads) in flight;
        // at kt==NT-2 nothing newer was issued, so drain fully for (NT-1).Xh1.
        if (kt < NT - 2) asm volatile("s_waitcnt vmcnt(6)" ::: "memory");
        else             asm volatile("s_waitcnt vmcnt(0)" ::: "memory");
        __builtin_amdgcn_sched_barrier(0);
        __builtin_amdgcn_s_barrier();
    }

    // ---- epilogue: D row = oc (quad*4+i), col = spatial (lane&15) ----
#pragma unroll
    for (int g = 0; g < 8; ++g) {
        const int mm = m0 + (g >> 2) * 128 + wm * 64 + (g & 3) * 16 + l16;
        const int bb = mm / PLANE;
        const int ss = mm - bb * PLANE;
        float* obase = out + (size_t)bb * (OC * PLANE) + ss;
#pragma unroll
        for (int f = 0; f < 4; ++f) {
            const int n = (f >> 1) * 128 + wn * 32 + (f & 1) * 16 + quad * 4;
#pragma unroll
            for (int i = 0; i < 4; ++i)
                obase[(size_t)(n + i) * PLANE] = acc[f][g][i];
        }
    }
}

extern "C" void kernel_launch(void* const* d_in, const int* in_sizes, int n_in,
                              void* d_out, int out_size, void* d_ws, size_t ws_size,
                              hipStream_t stream) {
    const float* x    = (const float*)d_in[0];
    const float* W    = (const float*)d_in[1];
    const float* bias = (const float*)d_in[2];
    float* out = (float*)d_out;

    u16* xpad = (u16*)d_ws;
    u16* w3   = xpad + XPAD_ELEMS;

    zero_border<<<232, 256, 0, stream>>>((uint4*)xpad);
    pad_tr<<<dim3(HH, BATCH), 256, 0, stream>>>(x, xpad);
    pack_w<<<(W3_ELEMS + 255) / 256, 256, 0, stream>>>(W, w3);

    conv_main<<<392, 512, 0, stream>>>(xpad, w3, bias, out);
}

// Round 2
// 215.574 us; speedup vs baseline: 1.0397x; 1.0397x over previous
//
#include <hip/hip_runtime.h>
#include <hip/hip_bf16.h>
#include <stdint.h>

typedef unsigned short u16;
typedef unsigned int   u32;
typedef __bf16 bf16x8 __attribute__((ext_vector_type(8)));
typedef float  f32x4  __attribute__((ext_vector_type(4)));

#define BATCH 32
#define CIN   128
#define HH    56
#define WW    56
#define OC    256
#define HP    58
#define WP    58
#define PLANE  (HH*WW)    // 3136
#define KDIM   1152       // CIN*9
#define NT     18         // K tiles of 64 (KDIM/64)

#define XPAD_ELEMS (BATCH*HP*WP*CIN)   // NHWC padded bf16: 13,778,944
#define W3_ELEMS   (OC*KDIM)           // 294,912 bf16

#define GLDS16(g, l) __builtin_amdgcn_global_load_lds( \
    (const __attribute__((address_space(1))) void*)(g), \
    (__attribute__((address_space(3))) void*)(l), 16, 0, 0)

// ---- prep 0: zero top/bottom padded rows (h=0 and h=57 per image) ----
__global__ void zero_border(uint4* __restrict__ xp4) {
    int i = blockIdx.x * 256 + threadIdx.x;       // uint4 index
    if (i >= 64 * 928) return;                    // 64 rows x 928 uint4/row
    int row = i / 928;
    int off = i - row * 928;
    int b = row >> 1;
    int h = (row & 1) ? (HP - 1) : 0;
    xp4[((size_t)(b * HP + h) * WP * CIN) / 8 + off] = (uint4){0, 0, 0, 0};
}

// ---- prep 1: NCHW fp32 -> NHWC bf16, interior + left/right borders ----
__global__ __launch_bounds__(256) void pad_tr(const float* __restrict__ x,
                                              u16* __restrict__ xpad) {
    __shared__ u16 T16[56 * 130];   // [w][c], +2 pad -> bank stride 65 dwords
    const int h = blockIdx.x;
    const int b = blockIdx.y;
    const int tid = threadIdx.x;

    const float* src = x + (size_t)b * CIN * PLANE + h * WW;
#pragma unroll
    for (int j = 0; j < 28; ++j) {              // 28*256 = 7168 = 128*56
        int flat = j * 256 + tid;
        int c = flat / 56;
        int w = flat - c * 56;
        float v = src[(size_t)c * PLANE + w];
        __hip_bfloat16 bv = __float2bfloat16(v);
        T16[w * 130 + c] = *(u16*)&bv;
    }
    __syncthreads();

    const u32* T32 = (const u32*)T16;
    uint4* dst = (uint4*)(xpad + (size_t)(b * HP + h + 1) * WP * CIN);
#pragma unroll
    for (int j = 0; j < 4; ++j) {
        int g = j * 256 + tid;
        if (g < 928) {
            int wp = g >> 4, cq = g & 15;       // 16 uint4 = 128 ch per wp
            uint4 v = (uint4){0, 0, 0, 0};
            if (wp >= 1 && wp <= 56) {
                int w = wp - 1;
                v.x = T32[w * 65 + cq * 4 + 0];
                v.y = T32[w * 65 + cq * 4 + 1];
                v.z = T32[w * 65 + cq * 4 + 2];
                v.w = T32[w * 65 + cq * 4 + 3];
            }
            dst[g] = v;
        }
    }
}

// ---- prep 2: W[OC][C*9] fp32 -> bf16, layout [T=18][oc 256][64k], with the
// 8-chunk rotation PRE-APPLIED so conv_main's W staging is a linear copy.
// K-tile T covers r = T>>1 (kh*3+kw), channels (T&1)*64 .. +63.
// Rotation rot = row & 7 (row = oc&127): position p stores true chunk
// ((p - rot) & 7).  NOTE: rot=(row>>1) is only conflict-free for 64-B rows
// (half-row bank offset complements the pair); at 128-B rows every row
// starts at bank 0, so rot must advance EVERY row -> rot = row & 7.
__global__ void pack_w(const float* __restrict__ W, u16* __restrict__ w3) {
    int o = blockIdx.x * blockDim.x + threadIdx.x;
    if (o >= W3_ELEMS) return;
    int T   = o >> 14;            // /16384
    int rem = o & 16383;
    int oc  = rem >> 6;
    int kk  = rem & 63;
    int p   = kk >> 3;
    int e   = kk & 7;
    int rot = oc & 7;             // row within half = oc&127; rot = row&7
    int c64 = ((p - rot) & 7) * 8 + e;
    int r   = T >> 1;
    int c128 = (T & 1) * 64 + c64;
    float val = W[oc * KDIM + c128 * 9 + r];
    __hip_bfloat16 bv = __float2bfloat16(val);
    w3[o] = *(u16*)&bv;
}

// ---------------- main: implicit GEMM, 256x256 tile, BK=64, 8-phase ----------
// 512 threads = 8 waves (2 spatial-half x 4 oc-quarter). Per-wave output is
// half-interleaved: oc cols {wn*32..+31} in BOTH oc-halves, spatial rows
// {wm*64..+63} in BOTH spatial-halves -> half-slot last-reads stagger:
//   Wh0: P1, Xh0: P1, Wh1: P2, Xh1: P3.
// Stage cadence (one half-tile = 2 GLDS16/thread per phase), WAR-safe since
// each stage targets a slot whose last ds_read was >=1 phase earlier:
//   P1: (t+1).Xh1   P2: (t+2).Wh0   P3: (t+2).Xh0   P4: (t+2).Wh1
// vmcnt(6) ONLY at P4 (3 half-tiles in flight) guarantees tile t+1 landed.
// Raw s_barrier (never __syncthreads) so the DMA queue is never drained to 0
// in steady state. setprio(1) around each 16-MFMA cluster.
// LDS rows are 128 B (64 bf16) = exactly 32 banks; chunk-rotation swizzle
// rot = row & 7 makes every aligned 8-lane group of a ds_read_b128 cover all
// 8 chunks (all 32 banks) exactly once -> conflict-free.  (^64 second-half
// read flips chunk bit 2 = +4 mod 8: still a bijection.)
__global__ __launch_bounds__(512, 2) void conv_main(
    const u16* __restrict__ xpad,
    const u16* __restrict__ w3,
    const float* __restrict__ bias,
    float* __restrict__ out)
{
    __shared__ __align__(16) u16 WL[2 * 2 * 128 * 64];  // [buf][half][128][64] 64KB
    __shared__ __align__(16) u16 XL[2 * 2 * 128 * 64];  // 64KB

    const int tid  = threadIdx.x;
    const int lane = tid & 63;
    const int wv   = tid >> 6;
    const int wm   = wv >> 2;       // spatial 64-row slice within each half
    const int wn   = wv & 3;        // oc 32-col slice within each half
    const int l16  = lane & 15;
    const int quad = lane >> 4;

    // XCD-aware swizzle: 392 = 8 * 49 (divisible -> simple form is bijective)
    const int bid  = blockIdx.x;
    const int tile = (bid & 7) * 49 + (bid >> 3);
    const int m0   = tile * 256;

    // ---- staging geometry: instr i covers rows (wv*2+i)*8..+7, pos lane&7 ----
    const int srow8 = lane >> 3;
    const int spos  = lane & 7;
    size_t xsrc[2][2];
#pragma unroll
    for (int h = 0; h < 2; ++h)
#pragma unroll
        for (int i = 0; i < 2; ++i) {
            int r  = (wv * 2 + i) * 8 + srow8;          // row within half
            int q  = (spos - (r & 7)) & 7;              // source chunk (r&7=srow8)
            int m  = m0 + h * 128 + r;
            int b  = m / PLANE;
            int s  = m - b * PLANE;
            int hh = s / WW;
            int ww = s - hh * WW;
            xsrc[h][i] = ((size_t)((b * HP + hh) * WP + ww) * CIN) * 2 + (size_t)q * 16;
        }
    const char* xb  = (const char*)xpad;
    const char* w3b = (const char*)w3;
    const int dstat     = wv * 2048;            // LDS dst (wave-uniform) base
    const int wsrc_lane = wv * 2048 + lane * 16;

    auto xkoff = [&](int kt) -> int {
        int r9 = kt >> 1;
        int kh = (r9 * 11) >> 5;                // r9/3 for r9 in 0..8
        int kw = r9 - kh * 3;
        return ((kh * WP + kw) * CIN + (kt & 1) * 64) * 2;
    };
    auto stageW = [&](int kt, int h) {
        const char* src = w3b + (size_t)kt * 32768 + h * 16384 + wsrc_lane;
        char* dst = (char*)WL + (kt & 1) * 32768 + h * 16384 + dstat;
        GLDS16(src,        dst);
        GLDS16(src + 1024, dst + 1024);
    };
    auto stageX = [&](int kt, int h, int xko) {
        char* dst = (char*)XL + (kt & 1) * 32768 + h * 16384 + dstat;
        GLDS16(xb + xsrc[h][0] + xko, dst);
        GLDS16(xb + xsrc[h][1] + xko, dst + 1024);
    };

    // frag ds_read byte offsets within a half-slot (s=0; s=1 is ^64)
    int woff[2], xoff[4];
#pragma unroll
    for (int j = 0; j < 2; ++j) {
        int r = wn * 32 + j * 16 + l16;
        woff[j] = r * 128 + (((quad + r) & 7) << 4);
    }
#pragma unroll
    for (int j = 0; j < 4; ++j) {
        int r = wm * 64 + j * 16 + l16;
        xoff[j] = r * 128 + (((quad + r) & 7) << 4);
    }

    f32x4 acc[4][8];
#pragma unroll
    for (int f = 0; f < 4; ++f) {
        const int ob = (f >> 1) * 128 + wn * 32 + (f & 1) * 16 + quad * 4;
        f32x4 bv = *(const f32x4*)&bias[ob];
#pragma unroll
        for (int g = 0; g < 8; ++g) acc[f][g] = bv;
    }

    // ---- prologue: tile0 full + tile1 {Wh0,Xh0,Wh1} (14 loads in flight) ----
    stageW(0, 0); stageW(0, 1);
    stageX(0, 0, xkoff(0)); stageX(0, 1, xkoff(0));
    stageW(1, 0); stageX(1, 0, xkoff(1)); stageW(1, 1);
    asm volatile("s_waitcnt vmcnt(6)" ::: "memory");   // tile0's 8 loads landed
    __builtin_amdgcn_sched_barrier(0);
    __builtin_amdgcn_s_barrier();

#pragma unroll 1
    for (int kt = 0; kt < NT; ++kt) {
        const char* Wb = (const char*)WL + (kt & 1) * 32768;
        const char* Xb = (const char*)XL + (kt & 1) * 32768;
        const bool st2 = (kt + 2 < NT);

        // ================= P1: Wh0 x Xh0 =================
        bf16x8 wlo[2][2], xlo[4][2];
#pragma unroll
        for (int j = 0; j < 2; ++j) {
            wlo[j][0] = *(const bf16x8*)(Wb + woff[j]);
            wlo[j][1] = *(const bf16x8*)(Wb + (woff[j] ^ 64));
        }
#pragma unroll
        for (int j = 0; j < 4; ++j) {
            xlo[j][0] = *(const bf16x8*)(Xb + xoff[j]);
            xlo[j][1] = *(const bf16x8*)(Xb + (xoff[j] ^ 64));
        }
        if (kt + 1 < NT) stageX(kt + 1, 1, xkoff(kt + 1));
        __builtin_amdgcn_s_barrier();
        asm volatile("s_waitcnt lgkmcnt(0)" ::: "memory");
        __builtin_amdgcn_sched_barrier(0);
        __builtin_amdgcn_s_setprio(1);
#pragma unroll
        for (int f = 0; f < 2; ++f)
#pragma unroll
            for (int g = 0; g < 4; ++g)
#pragma unroll
                for (int s = 0; s < 2; ++s)
                    acc[f][g] = __builtin_amdgcn_mfma_f32_16x16x32_bf16(
                        wlo[f][s], xlo[g][s], acc[f][g], 0, 0, 0);
        __builtin_amdgcn_s_setprio(0);
        __builtin_amdgcn_s_barrier();

        // ================= P2: Wh1 x Xh0 =================
        bf16x8 whi[2][2];
#pragma unroll
        for (int j = 0; j < 2; ++j) {
            whi[j][0] = *(const bf16x8*)(Wb + 16384 + woff[j]);
            whi[j][1] = *(const bf16x8*)(Wb + 16384 + (woff[j] ^ 64));
        }
        if (st2) stageW(kt + 2, 0);
        __builtin_amdgcn_s_barrier();
        asm volatile("s_waitcnt lgkmcnt(0)" ::: "memory");
        __builtin_amdgcn_sched_barrier(0);
        __builtin_amdgcn_s_setprio(1);
#pragma unroll
        for (int f = 0; f < 2; ++f)
#pragma unroll
            for (int g = 0; g < 4; ++g)
#pragma unroll
                for (int s = 0; s < 2; ++s)
                    acc[2 + f][g] = __builtin_amdgcn_mfma_f32_16x16x32_bf16(
                        whi[f][s], xlo[g][s], acc[2 + f][g], 0, 0, 0);
        __builtin_amdgcn_s_setprio(0);
        __builtin_amdgcn_s_barrier();

        // ================= P3: Wh0 x Xh1 =================
        bf16x8 xhi[4][2];
#pragma unroll
        for (int j = 0; j < 4; ++j) {
            xhi[j][0] = *(const bf16x8*)(Xb + 16384 + xoff[j]);
            xhi[j][1] = *(const bf16x8*)(Xb + 16384 + (xoff[j] ^ 64));
        }
        if (st2) stageX(kt + 2, 0, xkoff(kt + 2));
        __builtin_amdgcn_s_barrier();
        asm volatile("s_waitcnt lgkmcnt(0)" ::: "memory");
        __builtin_amdgcn_sched_barrier(0);
        __builtin_amdgcn_s_setprio(1);
#pragma unroll
        for (int f = 0; f < 2; ++f)
#pragma unroll
            for (int g = 0; g < 4; ++g)
#pragma unroll
                for (int s = 0; s < 2; ++s)
                    acc[f][4 + g] = __builtin_amdgcn_mfma_f32_16x16x32_bf16(
                        wlo[f][s], xhi[g][s], acc[f][4 + g], 0, 0, 0);
        __builtin_amdgcn_s_setprio(0);
        __builtin_amdgcn_s_barrier();

        // ================= P4: Wh1 x Xh1 (no ds_reads; all from regs) =======
        if (st2) stageW(kt + 2, 1);
        __builtin_amdgcn_s_barrier();
        __builtin_amdgcn_s_setprio(1);
#pragma unroll
        for (int f = 0; f < 2; ++f)
#pragma unroll
            for (int g = 0; g < 4; ++g)
#pragma unroll
                for (int s = 0; s < 2; ++s)
                    acc[2 + f][4 + g] = __builtin_amdgcn_mfma_f32_16x16x32_bf16(
                        whi[f][s], xhi[g][s], acc[2 + f][4 + g], 0, 0, 0);
        __builtin_amdgcn_s_setprio(0);
        // counted drain: steady state keeps 3 half-tiles (6 loads) in flight;
        // at kt==NT-2 nothing newer was issued, so drain fully for (NT-1).Xh1.
        if (kt < NT - 2) asm volatile("s_waitcnt vmcnt(6)" ::: "memory");
        else             asm volatile("s_waitcnt vmcnt(0)" ::: "memory");
        __builtin_amdgcn_sched_barrier(0);
        __builtin_amdgcn_s_barrier();
    }

    // ---- epilogue: D row = oc (quad*4+i), col = spatial (lane&15) ----
#pragma unroll
    for (int g = 0; g < 8; ++g) {
        const int mm = m0 + (g >> 2) * 128 + wm * 64 + (g & 3) * 16 + l16;
        const int bb = mm / PLANE;
        const int ss = mm - bb * PLANE;
        float* obase = out + (size_t)bb * (OC * PLANE) + ss;
#pragma unroll
        for (int f = 0; f < 4; ++f) {
            const int n = (f >> 1) * 128 + wn * 32 + (f & 1) * 16 + quad * 4;
#pragma unroll
            for (int i = 0; i < 4; ++i)
                obase[(size_t)(n + i) * PLANE] = acc[f][g][i];
        }
    }
}

extern "C" void kernel_launch(void* const* d_in, const int* in_sizes, int n_in,
                              void* d_out, int out_size, void* d_ws, size_t ws_size,
                              hipStream_t stream) {
    const float* x    = (const float*)d_in[0];
    const float* W    = (const float*)d_in[1];
    const float* bias = (const float*)d_in[2];
    float* out = (float*)d_out;

    u16* xpad = (u16*)d_ws;
    u16* w3   = xpad + XPAD_ELEMS;

    zero_border<<<232, 256, 0, stream>>>((uint4*)xpad);
    pad_tr<<<dim3(HH, BATCH), 256, 0, stream>>>(x, xpad);
    pack_w<<<(W3_ELEMS + 255) / 256, 256, 0, stream>>>(W, w3);

    conv_main<<<392, 512, 0, stream>>>(xpad, w3, bias, out);
}

// Round 4
// 214.665 us; speedup vs baseline: 1.0441x; 1.0042x over previous
//
#include <hip/hip_runtime.h>
#include <hip/hip_bf16.h>
#include <stdint.h>

typedef unsigned short u16;
typedef unsigned int   u32;
typedef __bf16 bf16x8 __attribute__((ext_vector_type(8)));
typedef float  f32x4  __attribute__((ext_vector_type(4)));

#define BATCH 32
#define CIN   128
#define HH    56
#define WW    56
#define OC    256
#define HP    58
#define WP    58
#define PLANE  (HH*WW)    // 3136
#define KDIM   1152       // CIN*9
#define NT     18         // K tiles of 64 (KDIM/64)

#define XPAD_ELEMS (BATCH*HP*WP*CIN)   // NHWC padded bf16: 13,778,944
#define W3_ELEMS   (OC*KDIM)           // 294,912 bf16

#define GLDS16(g, l) __builtin_amdgcn_global_load_lds( \
    (const __attribute__((address_space(1))) void*)(g), \
    (__attribute__((address_space(3))) void*)(l), 16, 0, 0)

// ---- prep 0: zero top/bottom padded rows (h=0 and h=57 per image) ----
__global__ void zero_border(uint4* __restrict__ xp4) {
    int i = blockIdx.x * 256 + threadIdx.x;       // uint4 index
    if (i >= 64 * 928) return;                    // 64 rows x 928 uint4/row
    int row = i / 928;
    int off = i - row * 928;
    int b = row >> 1;
    int h = (row & 1) ? (HP - 1) : 0;
    xp4[((size_t)(b * HP + h) * WP * CIN) / 8 + off] = (uint4){0, 0, 0, 0};
}

// ---- prep 1: NCHW fp32 -> NHWC bf16, interior + left/right borders ----
__global__ __launch_bounds__(256) void pad_tr(const float* __restrict__ x,
                                              u16* __restrict__ xpad) {
    __shared__ u16 T16[56 * 130];   // [w][c], +2 pad -> bank stride 65 dwords
    const int h = blockIdx.x;
    const int b = blockIdx.y;
    const int tid = threadIdx.x;

    const float* src = x + (size_t)b * CIN * PLANE + h * WW;
#pragma unroll
    for (int j = 0; j < 28; ++j) {              // 28*256 = 7168 = 128*56
        int flat = j * 256 + tid;
        int c = flat / 56;
        int w = flat - c * 56;
        float v = src[(size_t)c * PLANE + w];
        __hip_bfloat16 bv = __float2bfloat16(v);
        T16[w * 130 + c] = *(u16*)&bv;
    }
    __syncthreads();

    const u32* T32 = (const u32*)T16;
    uint4* dst = (uint4*)(xpad + (size_t)(b * HP + h + 1) * WP * CIN);
#pragma unroll
    for (int j = 0; j < 4; ++j) {
        int g = j * 256 + tid;
        if (g < 928) {
            int wp = g >> 4, cq = g & 15;       // 16 uint4 = 128 ch per wp
            uint4 v = (uint4){0, 0, 0, 0};
            if (wp >= 1 && wp <= 56) {
                int w = wp - 1;
                v.x = T32[w * 65 + cq * 4 + 0];
                v.y = T32[w * 65 + cq * 4 + 1];
                v.z = T32[w * 65 + cq * 4 + 2];
                v.w = T32[w * 65 + cq * 4 + 3];
            }
            dst[g] = v;
        }
    }
}

// ---- prep 2: W[OC][C*9] fp32 -> bf16, layout [T=18][oc 256][64k], rotation
// rot = row & 7 PRE-APPLIED (row = oc&127): position p stores true chunk
// ((p - rot) & 7).  128-B LDS rows start at bank 0 every row, so rotation
// must advance EVERY row.
__global__ void pack_w(const float* __restrict__ W, u16* __restrict__ w3) {
    int o = blockIdx.x * blockDim.x + threadIdx.x;
    if (o >= W3_ELEMS) return;
    int T   = o >> 14;            // /16384
    int rem = o & 16383;
    int oc  = rem >> 6;
    int kk  = rem & 63;
    int p   = kk >> 3;
    int e   = kk & 7;
    int rot = oc & 7;             // row within half = oc&127; rot = row&7
    int c64 = ((p - rot) & 7) * 8 + e;
    int r   = T >> 1;
    int c128 = (T & 1) * 64 + c64;
    float val = W[oc * KDIM + c128 * 9 + r];
    __hip_bfloat16 bv = __float2bfloat16(val);
    w3[o] = *(u16*)&bv;
}

// ---------------- main: implicit GEMM, 256x256 tile, BK=64 ------------------
// EARLY-ISSUE schedule (r3): all of tile t's ds_reads that are legal at P1
// (visibility established by prior P4's vmcnt+barrier) issue at the TOP of
// the iteration; staged lgkmcnt thresholds release each MFMA cluster as its
// operand group lands (DS ops complete in issue order).  xhi issues right
// after P2's MFMA (xlo regs die there -> register reuse keeps pressure flat).
// This overlaps the LDS drain with MFMA + barrier-sync and cuts barriers
// from 8/kt to 3/kt:
//   P1: issue wlo(4),xlo(8) | whi(4); stage (t+1).Xh1; lgkm(4)->first 12
//       done; MFMA W0X0; BAR(A)   [guards P2's stage of slot Wh0: all waves'
//       wlo reads complete before their own MFMA -> before BAR(A)]
//   P2: stage (t+2).Wh0; lgkm(0)->whi done; MFMA W1X0; issue xhi(8)
//       [no barrier: P3's stage hits slot Xh0 whose reads finished pre-BAR(A)]
//   P3: stage (t+2).Xh0; lgkm(0)->xhi done; MFMA W0X1; BAR(B)  [guards P4's
//       stage of slot Wh1: whi reads done before each wave's P2 MFMA]
//   P4: stage (t+2).Wh1; MFMA W1X1 (regs only); vmcnt(6); BAR(C) [tile t+1
//       DMA visible block-wide]
// vmcnt(6): 3 half-tiles (6 loads/wave) stay in flight; never drained to 0
// in steady state.  Stage cadence identical to the verified r2 kernel.
// LDS rows 128 B = 32 banks; chunk-rotation rot = row & 7 keeps every
// ds_read_b128 conflict-free (verified: SQ_LDS_BANK_CONFLICT = 0).
__global__ __launch_bounds__(512, 2) void conv_main(
    const u16* __restrict__ xpad,
    const u16* __restrict__ w3,
    const float* __restrict__ bias,
    float* __restrict__ out)
{
    __shared__ __align__(16) u16 WL[2 * 2 * 128 * 64];  // [buf][half][128][64] 64KB
    __shared__ __align__(16) u16 XL[2 * 2 * 128 * 64];  // 64KB

    const int tid  = threadIdx.x;
    const int lane = tid & 63;
    const int wv   = tid >> 6;
    const int wm   = wv >> 2;       // spatial 64-row slice within each half
    const int wn   = wv & 3;        // oc 32-col slice within each half
    const int l16  = lane & 15;
    const int quad = lane >> 4;

    // XCD-aware swizzle: 392 = 8 * 49 (divisible -> simple form is bijective)
    const int bid  = blockIdx.x;
    const int tile = (bid & 7) * 49 + (bid >> 3);
    const int m0   = tile * 256;

    // ---- staging geometry: instr i covers rows (wv*2+i)*8..+7, pos lane&7 ----
    const int srow8 = lane >> 3;
    const int spos  = lane & 7;
    size_t xsrc[2][2];
#pragma unroll
    for (int h = 0; h < 2; ++h)
#pragma unroll
        for (int i = 0; i < 2; ++i) {
            int r  = (wv * 2 + i) * 8 + srow8;          // row within half
            int q  = (spos - (r & 7)) & 7;              // source chunk (r&7=srow8)
            int m  = m0 + h * 128 + r;
            int b  = m / PLANE;
            int s  = m - b * PLANE;
            int hh = s / WW;
            int ww = s - hh * WW;
            xsrc[h][i] = ((size_t)((b * HP + hh) * WP + ww) * CIN) * 2 + (size_t)q * 16;
        }
    const char* xb  = (const char*)xpad;
    const char* w3b = (const char*)w3;
    const int dstat     = wv * 2048;            // LDS dst (wave-uniform) base
    const int wsrc_lane = wv * 2048 + lane * 16;

    auto xkoff = [&](int kt) -> int {
        int r9 = kt >> 1;
        int kh = (r9 * 11) >> 5;                // r9/3 for r9 in 0..8
        int kw = r9 - kh * 3;
        return ((kh * WP + kw) * CIN + (kt & 1) * 64) * 2;
    };
    auto stageW = [&](int kt, int h) {
        const char* src = w3b + (size_t)kt * 32768 + h * 16384 + wsrc_lane;
        char* dst = (char*)WL + (kt & 1) * 32768 + h * 16384 + dstat;
        GLDS16(src,        dst);
        GLDS16(src + 1024, dst + 1024);
    };
    auto stageX = [&](int kt, int h, int xko) {
        char* dst = (char*)XL + (kt & 1) * 32768 + h * 16384 + dstat;
        GLDS16(xb + xsrc[h][0] + xko, dst);
        GLDS16(xb + xsrc[h][1] + xko, dst + 1024);
    };

    // frag ds_read byte offsets within a half-slot (s=0; s=1 is ^64)
    int woff[2], xoff[4];
#pragma unroll
    for (int j = 0; j < 2; ++j) {
        int r = wn * 32 + j * 16 + l16;
        woff[j] = r * 128 + (((quad + r) & 7) << 4);
    }
#pragma unroll
    for (int j = 0; j < 4; ++j) {
        int r = wm * 64 + j * 16 + l16;
        xoff[j] = r * 128 + (((quad + r) & 7) << 4);
    }

    f32x4 acc[4][8];
#pragma unroll
    for (int f = 0; f < 4; ++f) {
        const int ob = (f >> 1) * 128 + wn * 32 + (f & 1) * 16 + quad * 4;
        f32x4 bv = *(const f32x4*)&bias[ob];
#pragma unroll
        for (int g = 0; g < 8; ++g) acc[f][g] = bv;
    }

    // ---- prologue: tile0 full + tile1 {Wh0,Xh0,Wh1} (14 loads in flight) ----
    stageW(0, 0); stageW(0, 1);
    stageX(0, 0, xkoff(0)); stageX(0, 1, xkoff(0));
    stageW(1, 0); stageX(1, 0, xkoff(1)); stageW(1, 1);
    asm volatile("s_waitcnt vmcnt(6)" ::: "memory");   // tile0's 8 loads landed
    __builtin_amdgcn_sched_barrier(0);
    __builtin_amdgcn_s_barrier();

#pragma unroll 1
    for (int kt = 0; kt < NT; ++kt) {
        const char* Wb = (const char*)WL + (kt & 1) * 32768;
        const char* Xb = (const char*)XL + (kt & 1) * 32768;
        const bool st2 = (kt + 2 < NT);

        // ===== P1: issue {wlo,xlo} then {whi}; stage; lgkm(4); MFMA W0X0 =====
        bf16x8 wlo[2][2], xlo[4][2], whi[2][2];
#pragma unroll
        for (int j = 0; j < 2; ++j) {
            wlo[j][0] = *(const bf16x8*)(Wb + woff[j]);
            wlo[j][1] = *(const bf16x8*)(Wb + (woff[j] ^ 64));
        }
#pragma unroll
        for (int j = 0; j < 4; ++j) {
            xlo[j][0] = *(const bf16x8*)(Xb + xoff[j]);
            xlo[j][1] = *(const bf16x8*)(Xb + (xoff[j] ^ 64));
        }
        __builtin_amdgcn_sched_barrier(0);      // pin group A before group B
#pragma unroll
        for (int j = 0; j < 2; ++j) {
            whi[j][0] = *(const bf16x8*)(Wb + 16384 + woff[j]);
            whi[j][1] = *(const bf16x8*)(Wb + 16384 + (woff[j] ^ 64));
        }
        __builtin_amdgcn_sched_barrier(0);
        if (kt + 1 < NT) stageX(kt + 1, 1, xkoff(kt + 1));
        asm volatile("s_waitcnt lgkmcnt(4)" ::: "memory");  // wlo+xlo landed
        __builtin_amdgcn_sched_barrier(0);
        __builtin_amdgcn_s_setprio(1);
#pragma unroll
        for (int f = 0; f < 2; ++f)
#pragma unroll
            for (int g = 0; g < 4; ++g)
#pragma unroll
                for (int s = 0; s < 2; ++s)
                    acc[f][g] = __builtin_amdgcn_mfma_f32_16x16x32_bf16(
                        wlo[f][s], xlo[g][s], acc[f][g], 0, 0, 0);
        __builtin_amdgcn_s_setprio(0);
        __builtin_amdgcn_s_barrier();           // BAR(A): A-group reads done

        // ===== P2: stage Wh0(t+2); lgkm(0) -> whi; MFMA W1X0; issue xhi =====
        if (st2) stageW(kt + 2, 0);
        asm volatile("s_waitcnt lgkmcnt(0)" ::: "memory");
        __builtin_amdgcn_sched_barrier(0);
        __builtin_amdgcn_s_setprio(1);
#pragma unroll
        for (int f = 0; f < 2; ++f)
#pragma unroll
            for (int g = 0; g < 4; ++g)
#pragma unroll
                for (int s = 0; s < 2; ++s)
                    acc[2 + f][g] = __builtin_amdgcn_mfma_f32_16x16x32_bf16(
                        whi[f][s], xlo[g][s], acc[2 + f][g], 0, 0, 0);
        __builtin_amdgcn_s_setprio(0);
        __builtin_amdgcn_sched_barrier(0);      // keep xhi issue after MFMA
        bf16x8 xhi[4][2];                       // xlo dead -> regs reused
#pragma unroll
        for (int j = 0; j < 4; ++j) {
            xhi[j][0] = *(const bf16x8*)(Xb + 16384 + xoff[j]);
            xhi[j][1] = *(const bf16x8*)(Xb + 16384 + (xoff[j] ^ 64));
        }
        __builtin_amdgcn_sched_barrier(0);
        // no barrier: P3's stage hits slot Xh0, whose reads finished pre-BAR(A)

        // ===== P3: stage Xh0(t+2); lgkm(0) -> xhi; MFMA W0X1 =====
        if (st2) stageX(kt + 2, 0, xkoff(kt + 2));
        asm volatile("s_waitcnt lgkmcnt(0)" ::: "memory");
        __builtin_amdgcn_sched_barrier(0);
        __builtin_amdgcn_s_setprio(1);
#pragma unroll
        for (int f = 0; f < 2; ++f)
#pragma unroll
            for (int g = 0; g < 4; ++g)
#pragma unroll
                for (int s = 0; s < 2; ++s)
                    acc[f][4 + g] = __builtin_amdgcn_mfma_f32_16x16x32_bf16(
                        wlo[f][s], xhi[g][s], acc[f][4 + g], 0, 0, 0);
        __builtin_amdgcn_s_setprio(0);
        __builtin_amdgcn_s_barrier();           // BAR(B): whi reads done

        // ===== P4: stage Wh1(t+2); MFMA W1X1 (regs only); vmcnt; BAR(C) =====
        if (st2) stageW(kt + 2, 1);
        __builtin_amdgcn_s_setprio(1);
#pragma unroll
        for (int f = 0; f < 2; ++f)
#pragma unroll
            for (int g = 0; g < 4; ++g)
#pragma unroll
                for (int s = 0; s < 2; ++s)
                    acc[2 + f][4 + g] = __builtin_amdgcn_mfma_f32_16x16x32_bf16(
                        whi[f][s], xhi[g][s], acc[2 + f][4 + g], 0, 0, 0);
        __builtin_amdgcn_s_setprio(0);
        // counted drain: steady state keeps 3 half-tiles (6 loads) in flight;
        // at kt==NT-2 nothing newer was issued, so drain fully for (NT-1).Xh1.
        if (kt < NT - 2) asm volatile("s_waitcnt vmcnt(6)" ::: "memory");
        else             asm volatile("s_waitcnt vmcnt(0)" ::: "memory");
        __builtin_amdgcn_sched_barrier(0);
        __builtin_amdgcn_s_barrier();           // BAR(C): tile t+1 visible
    }

    // ---- epilogue: D row = oc (quad*4+i), col = spatial (lane&15) ----
#pragma unroll
    for (int g = 0; g < 8; ++g) {
        const int mm = m0 + (g >> 2) * 128 + wm * 64 + (g & 3) * 16 + l16;
        const int bb = mm / PLANE;
        const int ss = mm - bb * PLANE;
        float* obase = out + (size_t)bb * (OC * PLANE) + ss;
#pragma unroll
        for (int f = 0; f < 4; ++f) {
            const int n = (f >> 1) * 128 + wn * 32 + (f & 1) * 16 + quad * 4;
#pragma unroll
            for (int i = 0; i < 4; ++i)
                obase[(size_t)(n + i) * PLANE] = acc[f][g][i];
        }
    }
}

extern "C" void kernel_launch(void* const* d_in, const int* in_sizes, int n_in,
                              void* d_out, int out_size, void* d_ws, size_t ws_size,
                              hipStream_t stream) {
    const float* x    = (const float*)d_in[0];
    const float* W    = (const float*)d_in[1];
    const float* bias = (const float*)d_in[2];
    float* out = (float*)d_out;

    u16* xpad = (u16*)d_ws;
    u16* w3   = xpad + XPAD_ELEMS;

    zero_border<<<232, 256, 0, stream>>>((uint4*)xpad);
    pad_tr<<<dim3(HH, BATCH), 256, 0, stream>>>(x, xpad);
    pack_w<<<(W3_ELEMS + 255) / 256, 256, 0, stream>>>(W, w3);

    conv_main<<<392, 512, 0, stream>>>(xpad, w3, bias, out);
}